// Round 3
// baseline (3377.205 us; speedup 1.0000x reference)
//
#include <hip/hip_runtime.h>

#define CIN  32
#define COUT 64
#define KOFF 27
#define TILE 256           // output rows per block; LDS acc = 256*64*4 = 64 KB
#define EPS  1e-5f

// ---------------- CSR build: counting sort by (out_tile, k) ----------------

__global__ __launch_bounds__(256) void hist_kernel(
    const int* __restrict__ out_idx, int* __restrict__ hist, int M)
{
    const int m = blockIdx.x * 256 + threadIdx.x;
    const int k = blockIdx.y;
    if (m < M) {
        const int ok = out_idx[(size_t)k * M + m];
        atomicAdd(&hist[(ok >> 8) * KOFF + k], 1);   // bins are L2-resident (small)
    }
}

// Single-block exclusive scan over B bins (B ~= 53K). Writes offsets AND cursor copy.
__global__ __launch_bounds__(1024) void scan_kernel(
    const int* __restrict__ hist, int* __restrict__ off, int* __restrict__ cur, int B)
{
    __shared__ int part[1024];
    const int tid = threadIdx.x;
    const int chunk = (B + 1023) / 1024;
    const int base = tid * chunk;
    int sum = 0;
    for (int j = 0; j < chunk; ++j) { int i = base + j; if (i < B) sum += hist[i]; }
    part[tid] = sum;
    __syncthreads();
    for (int d = 1; d < 1024; d <<= 1) {          // inclusive Hillis-Steele
        int v = (tid >= d) ? part[tid - d] : 0;
        __syncthreads();
        part[tid] += v;
        __syncthreads();
    }
    int run = part[tid] - sum;                     // exclusive prefix
    for (int j = 0; j < chunk; ++j) {
        int i = base + j;
        if (i < B) { off[i] = run; cur[i] = run; run += hist[i]; }
    }
    if (tid == 1023) off[B] = run;
}

// Record pack: ik (19b) | k (5b) << 19 | local_row (8b) << 24
__global__ __launch_bounds__(256) void fill_kernel(
    const int* __restrict__ in_idx, const int* __restrict__ out_idx,
    int* __restrict__ cur, unsigned* __restrict__ recs, int M)
{
    const int m = blockIdx.x * 256 + threadIdx.x;
    const int k = blockIdx.y;
    if (m < M) {
        const int ok  = out_idx[(size_t)k * M + m];
        const int ik  = in_idx [(size_t)k * M + m];
        const int bin = (ok >> 8) * KOFF + k;
        const int pos = atomicAdd(&cur[bin], 1);
        recs[pos] = (unsigned)ik | ((unsigned)k << 19) | ((unsigned)(ok & 255) << 24);
    }
}

// ---------------- main: gather + LDS-tile accumulate + fused BN/ReLU ----------------
// One block per 256-row output tile. Wave w handles kernel offsets k = w, w+8, ...
// so k is wave-uniform -> Wk column lives in 32 VGPRs (no LDS/L2 W traffic in loop).
// Per pair: broadcast-load feats row (8x float4), 32 reg FMAs, one ds_add_f32.
__global__ __launch_bounds__(512, 4) void conv_main(
    const float* __restrict__ feats, const float* __restrict__ W,
    const int* __restrict__ off, const unsigned* __restrict__ recs,
    const float* __restrict__ gamma, const float* __restrict__ beta,
    const float* __restrict__ rmean, const float* __restrict__ rvar,
    float* __restrict__ out, int N)
{
    __shared__ float acc[TILE * COUT];            // 64 KB
    __shared__ float sc[COUT], sh[COUT];
    const int tid  = threadIdx.x;
    const int tile = blockIdx.x;

    float4* acc4 = (float4*)acc;
    for (int i = tid; i < TILE * COUT / 4; i += 512) acc4[i] = make_float4(0, 0, 0, 0);
    if (tid < COUT) {
        const float inv = rsqrtf(rvar[tid] + EPS);
        const float s = inv * gamma[tid];
        sc[tid] = s; sh[tid] = beta[tid] - rmean[tid] * s;
    }
    __syncthreads();

    const int lane = tid & 63;
    const int wave = tid >> 6;

    for (int k = wave; k < KOFF; k += 8) {
        const int seg = tile * KOFF + k;
        const int s = off[seg], e = off[seg + 1];
        if (s >= e) continue;
        float w[CIN];
        const float* Wk = W + (size_t)k * (CIN * COUT);
        #pragma unroll
        for (int c = 0; c < CIN; ++c) w[c] = Wk[c * COUT + lane];  // coalesced, L2-hot
        for (int r = s; r < e; ++r) {
            const unsigned rec = recs[r];
            const int ik    = rec & 0x7FFFF;
            const int local = rec >> 24;
            const float4* f4 = (const float4*)(feats + (size_t)ik * CIN);
            float a = 0.f;
            #pragma unroll
            for (int c4 = 0; c4 < CIN / 4; ++c4) {
                const float4 f = f4[c4];             // wave-uniform broadcast load
                a += f.x * w[c4*4+0] + f.y * w[c4*4+1] + f.z * w[c4*4+2] + f.w * w[c4*4+3];
            }
            atomicAdd(&acc[local * COUT + lane], a); // ds_add_f32, bank-conflict-free
        }
    }
    __syncthreads();

    const int base = tile * TILE;
    for (int i = tid; i < TILE * COUT / 4; i += 512) {
        const int row = i >> 4;                      // (i*4)/64
        if (base + row < N) {
            float4 v = acc4[i];
            const int c0 = (i & 15) * 4;
            v.x = fmaxf(v.x * sc[c0+0] + sh[c0+0], 0.f);
            v.y = fmaxf(v.y * sc[c0+1] + sh[c0+1], 0.f);
            v.z = fmaxf(v.z * sc[c0+2] + sh[c0+2], 0.f);
            v.w = fmaxf(v.w * sc[c0+3] + sh[c0+3], 0.f);
            ((float4*)out)[(size_t)base * (COUT / 4) + i] = v;
        }
    }
}

// ---------------- fallback (round-2 path) if workspace is too small ----------------

__global__ __launch_bounds__(256) void conv_scatter(
    const float* __restrict__ feats, const float* __restrict__ W,
    const int* __restrict__ in_idx, const int* __restrict__ out_idx,
    float* __restrict__ out, int M)
{
    __shared__ float Wl[CIN * COUT];
    const int k = blockIdx.x, tid = threadIdx.x;
    const float* Wk = W + (size_t)k * (CIN * COUT);
    for (int i = tid; i < CIN * COUT; i += 256) Wl[i] = Wk[i];
    __syncthreads();
    const int lane = tid & 63, wave = tid >> 6;
    const int wavesTotal = gridDim.y * 4;
    const int* ikb = in_idx + (size_t)k * M;
    const int* okb = out_idx + (size_t)k * M;
    for (int m = blockIdx.y * 4 + wave; m < M; m += wavesTotal) {
        const int ik = ikb[m], ok = okb[m];
        const float4* f4 = (const float4*)(feats + (size_t)ik * CIN);
        float acc = 0.f;
        #pragma unroll
        for (int c0 = 0; c0 < CIN / 4; ++c0) {
            float4 f = f4[c0];
            acc += f.x * Wl[(c0*4+0)*COUT + lane] + f.y * Wl[(c0*4+1)*COUT + lane]
                 + f.z * Wl[(c0*4+2)*COUT + lane] + f.w * Wl[(c0*4+3)*COUT + lane];
        }
        atomicAdd(out + (size_t)ok * COUT + lane, acc);
    }
}

__global__ __launch_bounds__(256) void bn_relu(
    float* __restrict__ out, const float* __restrict__ gamma, const float* __restrict__ beta,
    const float* __restrict__ rmean, const float* __restrict__ rvar, int total4)
{
    __shared__ float scale[COUT], shift[COUT];
    if (threadIdx.x < COUT) {
        const int c = threadIdx.x;
        const float inv = rsqrtf(rvar[c] + EPS);
        const float s = inv * gamma[c];
        scale[c] = s; shift[c] = beta[c] - rmean[c] * s;
    }
    __syncthreads();
    const int stride = gridDim.x * blockDim.x;
    for (int i = blockIdx.x * blockDim.x + threadIdx.x; i < total4; i += stride) {
        float4 v = ((const float4*)out)[i];
        const int c0 = (i * 4) & (COUT - 1);
        v.x = fmaxf(v.x * scale[c0+0] + shift[c0+0], 0.f);
        v.y = fmaxf(v.y * scale[c0+1] + shift[c0+1], 0.f);
        v.z = fmaxf(v.z * scale[c0+2] + shift[c0+2], 0.f);
        v.w = fmaxf(v.w * scale[c0+3] + shift[c0+3], 0.f);
        ((float4*)out)[i] = v;
    }
}

extern "C" void kernel_launch(void* const* d_in, const int* in_sizes, int n_in,
                              void* d_out, int out_size, void* d_ws, size_t ws_size,
                              hipStream_t stream) {
    const float* feats  = (const float*)d_in[0];
    const float* W      = (const float*)d_in[1];
    const float* gamma  = (const float*)d_in[2];
    const float* beta   = (const float*)d_in[3];
    const float* rmean  = (const float*)d_in[4];
    const float* rvar   = (const float*)d_in[5];
    const int*   in_idx  = (const int*)d_in[6];
    const int*   out_idx = (const int*)d_in[7];
    float* out = (float*)d_out;

    const int N = in_sizes[0] / CIN;
    const int M = in_sizes[6] / KOFF;
    const int ntiles = (N + TILE - 1) / TILE;
    const int B = ntiles * KOFF;
    const size_t total_pairs = (size_t)KOFF * M;
    const size_t needed = (size_t)(3 * B + 1) * 4 + total_pairs * 4;

    if (ws_size >= needed && N < (1 << 19)) {
        int* hist = (int*)d_ws;
        int* off  = hist + B;
        int* cur  = off + B + 1;
        unsigned* recs = (unsigned*)(cur + B);

        hipMemsetAsync(hist, 0, (size_t)B * 4, stream);
        dim3 g((M + 255) / 256, KOFF);
        hist_kernel<<<g, 256, 0, stream>>>(out_idx, hist, M);
        scan_kernel<<<1, 1024, 0, stream>>>(hist, off, cur, B);
        fill_kernel<<<g, 256, 0, stream>>>(in_idx, out_idx, cur, recs, M);
        conv_main<<<ntiles, 512, 0, stream>>>(feats, W, off, recs,
                                              gamma, beta, rmean, rvar, out, N);
    } else {
        hipMemsetAsync(out, 0, (size_t)N * COUT * sizeof(float), stream);
        dim3 grid(KOFF, 512);
        conv_scatter<<<grid, 256, 0, stream>>>(feats, W, in_idx, out_idx, out, M);
        const int total4 = N * COUT / 4;
        int blocks = (total4 + 255) / 256;
        if (blocks > 2048) blocks = 2048;
        bn_relu<<<blocks, 256, 0, stream>>>(out, gamma, beta, rmean, rvar, total4);
    }
}

// Round 4
// 2863.585 us; speedup vs baseline: 1.1794x; 1.1794x over previous
//
#include <hip/hip_runtime.h>

#define CIN  32
#define COUT 64
#define KOFF 27
#define TILE 128           // output rows per block; LDS acc = 128*64*4 = 32 KB
#define EPS  1e-5f

// ================= cap-based build (no hist/scan) =================
// bin = (ok>>7)*27 + k. Poisson(64) per bin; CAP>=128 -> overflow P ~ 7e-8.
__global__ __launch_bounds__(256) void fill_cap(
    const int* __restrict__ in_idx, const int* __restrict__ out_idx,
    int* __restrict__ cnt, unsigned* __restrict__ recs, int M, int cap)
{
    const int m = blockIdx.x * 256 + threadIdx.x;
    const int k = blockIdx.y;
    if (m < M) {
        const int ok = out_idx[(size_t)k * M + m];
        const int ik = in_idx [(size_t)k * M + m];
        const int bin = (ok >> 7) * KOFF + k;
        const int pos = atomicAdd(&cnt[bin], 1);
        if (pos < cap)
            recs[(size_t)bin * cap + pos] = (unsigned)ik | ((unsigned)(ok & 127) << 19);
    }
}

// ================= exact CSR build (fallback when ws is small) =================
__global__ __launch_bounds__(256) void hist_kernel(
    const int* __restrict__ out_idx, int* __restrict__ hist, int M)
{
    const int m = blockIdx.x * 256 + threadIdx.x;
    const int k = blockIdx.y;
    if (m < M) {
        const int ok = out_idx[(size_t)k * M + m];
        atomicAdd(&hist[(ok >> 7) * KOFF + k], 1);
    }
}

__global__ __launch_bounds__(1024) void scan_kernel(
    const int* __restrict__ hist, int* __restrict__ off, int* __restrict__ cur, int B)
{
    __shared__ int part[1024];
    const int tid = threadIdx.x;
    const int chunk = (B + 1023) / 1024;
    const int base = tid * chunk;
    int sum = 0;
    for (int j = 0; j < chunk; ++j) { int i = base + j; if (i < B) sum += hist[i]; }
    part[tid] = sum;
    __syncthreads();
    for (int d = 1; d < 1024; d <<= 1) {
        int v = (tid >= d) ? part[tid - d] : 0;
        __syncthreads();
        part[tid] += v;
        __syncthreads();
    }
    int run = part[tid] - sum;
    for (int j = 0; j < chunk; ++j) {
        int i = base + j;
        if (i < B) { off[i] = run; cur[i] = run; run += hist[i]; }
    }
    if (tid == 1023) off[B] = run;
}

__global__ __launch_bounds__(256) void fill_exact(
    const int* __restrict__ in_idx, const int* __restrict__ out_idx,
    int* __restrict__ cur, unsigned* __restrict__ recs, int M)
{
    const int m = blockIdx.x * 256 + threadIdx.x;
    const int k = blockIdx.y;
    if (m < M) {
        const int ok = out_idx[(size_t)k * M + m];
        const int ik = in_idx [(size_t)k * M + m];
        const int bin = (ok >> 7) * KOFF + k;
        const int pos = atomicAdd(&cur[bin], 1);
        recs[pos] = (unsigned)ik | ((unsigned)(ok & 127) << 19);
    }
}

// ================= main: gather + LDS-tile accumulate + fused BN/ReLU =================
// One block per 128-row output tile. Wave w handles k = w, w+8, ... (k wave-uniform ->
// Wk column in 32 VGPRs). Per record: 8 broadcast float4 loads, 32 FMAs, 1 ds_add_f32.
template <bool CAPMODE>
__global__ __launch_bounds__(512, 6) void conv_main(
    const float* __restrict__ feats, const float* __restrict__ W,
    const int* __restrict__ seg,            // CAPMODE: cnt[B]; else off[B+1]
    const unsigned* __restrict__ recs,
    const float* __restrict__ gamma, const float* __restrict__ beta,
    const float* __restrict__ rmean, const float* __restrict__ rvar,
    float* __restrict__ out, int N, int cap)
{
    __shared__ float acc[TILE * COUT];      // 32 KB
    __shared__ float sc[COUT], sh[COUT];
    const int tid  = threadIdx.x;
    const int tile = blockIdx.x;

    float4* acc4 = (float4*)acc;
    #pragma unroll
    for (int i = 0; i < TILE * COUT / 4 / 512; ++i)
        acc4[tid + i * 512] = make_float4(0, 0, 0, 0);
    if (tid < COUT) {
        const float inv = rsqrtf(rvar[tid] + EPS);
        const float s = inv * gamma[tid];
        sc[tid] = s; sh[tid] = beta[tid] - rmean[tid] * s;
    }
    __syncthreads();

    const int lane = tid & 63;
    const int wave = tid >> 6;

    for (int k = wave; k < KOFF; k += 8) {
        const int bin = tile * KOFF + k;
        size_t s; int n;
        if (CAPMODE) {
            n = seg[bin]; if (n > cap) n = cap;
            s = (size_t)bin * cap;
        } else {
            const int s0 = seg[bin];
            n = seg[bin + 1] - s0;
            s = (size_t)s0;
        }
        if (n <= 0) continue;

        float w[CIN];
        const float* Wk = W + (size_t)k * (CIN * COUT);
        #pragma unroll
        for (int c = 0; c < CIN; ++c) w[c] = Wk[c * COUT + lane];

        const unsigned* rp = recs + s;
        for (int r = 0; r < n; ++r) {
            const unsigned rec = rp[r];
            const int ik    = rec & 0x7FFFF;
            const int local = rec >> 19;
            const float4* f4 = (const float4*)(feats + (size_t)ik * CIN);
            float a = 0.f;
            #pragma unroll
            for (int c4 = 0; c4 < CIN / 4; ++c4) {
                const float4 f = f4[c4];            // wave-uniform broadcast load
                a += f.x * w[c4*4+0] + f.y * w[c4*4+1] + f.z * w[c4*4+2] + f.w * w[c4*4+3];
            }
            atomicAdd(&acc[local * COUT + lane], a); // ds_add_f32, conflict-free
        }
    }
    __syncthreads();

    const int base = tile * TILE;
    #pragma unroll
    for (int j = 0; j < TILE * COUT / 4 / 512; ++j) {
        const int i = tid + j * 512;
        const int row = i >> 4;
        if (base + row < N) {
            float4 v = acc4[i];
            const int c0 = (i & 15) * 4;
            v.x = fmaxf(v.x * sc[c0+0] + sh[c0+0], 0.f);
            v.y = fmaxf(v.y * sc[c0+1] + sh[c0+1], 0.f);
            v.z = fmaxf(v.z * sc[c0+2] + sh[c0+2], 0.f);
            v.w = fmaxf(v.w * sc[c0+3] + sh[c0+3], 0.f);
            ((float4*)out)[(size_t)base * (COUT / 4) + i] = v;
        }
    }
}

// ================= last-resort fallback (round-2 path) =================
__global__ __launch_bounds__(256) void conv_scatter(
    const float* __restrict__ feats, const float* __restrict__ W,
    const int* __restrict__ in_idx, const int* __restrict__ out_idx,
    float* __restrict__ out, int M)
{
    __shared__ float Wl[CIN * COUT];
    const int k = blockIdx.x, tid = threadIdx.x;
    const float* Wk = W + (size_t)k * (CIN * COUT);
    for (int i = tid; i < CIN * COUT; i += 256) Wl[i] = Wk[i];
    __syncthreads();
    const int lane = tid & 63, wave = tid >> 6;
    const int wavesTotal = gridDim.y * 4;
    const int* ikb = in_idx + (size_t)k * M;
    const int* okb = out_idx + (size_t)k * M;
    for (int m = blockIdx.y * 4 + wave; m < M; m += wavesTotal) {
        const int ik = ikb[m], ok = okb[m];
        const float4* f4 = (const float4*)(feats + (size_t)ik * CIN);
        float acc = 0.f;
        #pragma unroll
        for (int c0 = 0; c0 < CIN / 4; ++c0) {
            float4 f = f4[c0];
            acc += f.x * Wl[(c0*4+0)*COUT + lane] + f.y * Wl[(c0*4+1)*COUT + lane]
                 + f.z * Wl[(c0*4+2)*COUT + lane] + f.w * Wl[(c0*4+3)*COUT + lane];
        }
        atomicAdd(out + (size_t)ok * COUT + lane, acc);
    }
}

__global__ __launch_bounds__(256) void bn_relu(
    float* __restrict__ out, const float* __restrict__ gamma, const float* __restrict__ beta,
    const float* __restrict__ rmean, const float* __restrict__ rvar, int total4)
{
    __shared__ float scale[COUT], shift[COUT];
    if (threadIdx.x < COUT) {
        const int c = threadIdx.x;
        const float inv = rsqrtf(rvar[c] + EPS);
        const float s = inv * gamma[c];
        scale[c] = s; shift[c] = beta[c] - rmean[c] * s;
    }
    __syncthreads();
    const int stride = gridDim.x * blockDim.x;
    for (int i = blockIdx.x * blockDim.x + threadIdx.x; i < total4; i += stride) {
        float4 v = ((const float4*)out)[i];
        const int c0 = (i * 4) & (COUT - 1);
        v.x = fmaxf(v.x * scale[c0+0] + shift[c0+0], 0.f);
        v.y = fmaxf(v.y * scale[c0+1] + shift[c0+1], 0.f);
        v.z = fmaxf(v.z * scale[c0+2] + shift[c0+2], 0.f);
        v.w = fmaxf(v.w * scale[c0+3] + shift[c0+3], 0.f);
        ((float4*)out)[i] = v;
    }
}

extern "C" void kernel_launch(void* const* d_in, const int* in_sizes, int n_in,
                              void* d_out, int out_size, void* d_ws, size_t ws_size,
                              hipStream_t stream) {
    const float* feats  = (const float*)d_in[0];
    const float* W      = (const float*)d_in[1];
    const float* gamma  = (const float*)d_in[2];
    const float* beta   = (const float*)d_in[3];
    const float* rmean  = (const float*)d_in[4];
    const float* rvar   = (const float*)d_in[5];
    const int*   in_idx  = (const int*)d_in[6];
    const int*   out_idx = (const int*)d_in[7];
    float* out = (float*)d_out;

    const int N = in_sizes[0] / CIN;
    const int M = in_sizes[6] / KOFF;
    const int ntiles = (N + TILE - 1) / TILE;
    const int B = ntiles * KOFF;
    const size_t total_pairs = (size_t)KOFF * M;

    const int CAP = 160;  // Poisson(64): P(bin>=160) ~ 1e-22; 128 would also do
    const size_t cap_need   = (size_t)B * 4 + (size_t)B * CAP * 4;
    const size_t exact_need = (size_t)(3 * B + 1) * 4 + total_pairs * 4;
    dim3 g((M + 255) / 256, KOFF);

    if (N < (1 << 19) && ws_size >= cap_need) {
        int* cnt = (int*)d_ws;
        unsigned* recs = (unsigned*)(cnt + B);
        hipMemsetAsync(cnt, 0, (size_t)B * 4, stream);
        fill_cap<<<g, 256, 0, stream>>>(in_idx, out_idx, cnt, recs, M, CAP);
        conv_main<true><<<ntiles, 512, 0, stream>>>(feats, W, cnt, recs,
                                                    gamma, beta, rmean, rvar, out, N, CAP);
    } else if (N < (1 << 19) && ws_size >= exact_need) {
        int* hist = (int*)d_ws;
        int* off  = hist + B;
        int* cur  = off + B + 1;
        unsigned* recs = (unsigned*)(cur + B);
        hipMemsetAsync(hist, 0, (size_t)B * 4, stream);
        hist_kernel<<<g, 256, 0, stream>>>(out_idx, hist, M);
        scan_kernel<<<1, 1024, 0, stream>>>(hist, off, cur, B);
        fill_exact<<<g, 256, 0, stream>>>(in_idx, out_idx, cur, recs, M);
        conv_main<false><<<ntiles, 512, 0, stream>>>(feats, W, off, recs,
                                                     gamma, beta, rmean, rvar, out, N, 0);
    } else {
        hipMemsetAsync(out, 0, (size_t)N * COUT * sizeof(float), stream);
        dim3 grid(KOFF, 512);
        conv_scatter<<<grid, 256, 0, stream>>>(feats, W, in_idx, out_idx, out, M);
        const int total4 = N * COUT / 4;
        int blocks = (total4 + 255) / 256;
        if (blocks > 2048) blocks = 2048;
        bn_relu<<<blocks, 256, 0, stream>>>(out, gamma, beta, rmean, rvar, total4);
    }
}